// Round 1
// baseline (333.128 us; speedup 1.0000x reference)
//
#include <hip/hip_runtime.h>

#define NPAIR 96
#define MAXB 64
#define CAP 256

// bce_logits(t, x) = max(x,0) - x*t + log1p(exp(-|x|))
__device__ __forceinline__ float bce_f(float t, float x) {
    return fmaxf(x, 0.f) - x * t + log1pf(expf(-fabsf(x)));
}

__device__ const int   d_Stab[3]  = {13, 26, 52};
__device__ const int   d_n0tab[3] = {0, 169, 845};
__device__ const float d_anc[9][2] = {
    {116.f, 90.f}, {156.f, 198.f}, {373.f, 326.f},
    { 30.f, 61.f}, { 62.f, 45.f}, { 59.f, 119.f},
    { 10.f, 13.f}, { 16.f, 30.f}, { 33.f, 23.f}};

// One block per (batch, layer) pair. Builds:
//  - bitmap of positive cells (ballot words, 128 u64 per pair)
//  - ordered (by flat cell index) gt box list, capped at 64  == top_k semantics
//  - counts[pair] = min(#positives, 64)
// Also zeroes d_out (runs before loss kernel in stream order).
__global__ __launch_bounds__(256) void gather_k(
    const float* __restrict__ yt, float* __restrict__ boxes,
    int* __restrict__ counts, unsigned long long* __restrict__ bmp_all,
    float* __restrict__ out)
{
    int pair = blockIdx.x;
    int tid = threadIdx.x;
    if (pair == 0 && tid < 32) out[tid] = 0.f;
    int b = pair / 3;
    int l = pair - b * 3;
    int S = d_Stab[l];
    int nCells = S * S * 3;
    const float* ybase = yt + (long long)(b * 3549 + d_n0tab[l]) * 255;
    unsigned long long* bmp = bmp_all + (long long)pair * 128;

    __shared__ int sidx[CAP];
    __shared__ int scnt;
    if (tid == 0) scnt = 0;
    __syncthreads();

    // Phase 1: issue all obj loads up-front (independent -> latency hidden)
    float ov[32];
#pragma unroll
    for (int k = 0; k < 32; ++k) {
        int c = tid + (k << 8);
        ov[k] = (c < nCells) ? ybase[(long long)c * 85] : 0.f;
    }
    int lane = tid & 63;
    int wv = tid >> 6;
#pragma unroll
    for (int k = 0; k < 32; ++k) {
        int c = tid + (k << 8);
        bool pos = ov[k] > 0.5f;
        unsigned long long mask = __ballot(pos);
        if (lane == 0) bmp[k * 4 + wv] = mask;  // word (c>>6) == k*4+wv
        if (pos) {
            int slot = atomicAdd(&scnt, 1);
            if (slot < CAP) sidx[slot] = c;
        }
        (void)c;
    }
    __syncthreads();

    // Phase 2: rank positives by cell index (stable top_k order), write boxes
    int cnt = scnt;
    if (cnt > CAP) cnt = CAP;
    for (int i = tid; i < cnt; i += 256) {
        int myidx = sidx[i];
        int rank = 0;
        for (int j = 0; j < cnt; ++j) rank += (sidx[j] < myidx) ? 1 : 0;
        if (rank < MAXB) {
            const float* cell = ybase + (long long)myidx * 85;
            float* dst = boxes + ((long long)pair * MAXB + rank) * 4;
            dst[0] = cell[1]; dst[1] = cell[2]; dst[2] = cell[3]; dst[3] = cell[4];
        }
    }
    if (tid == 0) counts[pair] = cnt < MAXB ? cnt : MAXB;
}

// One thread per cell. Blocks per batch: 2 (13x13) + 8 (26x26) + 32 (52x52) = 42.
__global__ __launch_bounds__(256) void loss_k(
    const float* __restrict__ yt,
    const float* __restrict__ p13,
    const float* __restrict__ p26,
    const float* __restrict__ p52,
    const float* __restrict__ boxes,
    const int* __restrict__ counts,
    const unsigned long long* __restrict__ bmp_all,
    float* __restrict__ out)
{
    int bid = blockIdx.x;
    int b = bid / 42;
    int j = bid - b * 42;
    int l, blk;
    if (j < 2)       { l = 0; blk = j; }
    else if (j < 10) { l = 1; blk = j - 2; }
    else             { l = 2; blk = j - 10; }

    int S = d_Stab[l];
    int nCells = S * S * 3;
    int pair = b * 3 + l;

    __shared__ float sb[MAXB * 4];
    int count = counts[pair];
    {
        int n4 = count * 4;
        for (int i = threadIdx.x; i < n4; i += 256)
            sb[i] = boxes[(long long)pair * MAXB * 4 + i];
    }
    __syncthreads();

    const unsigned long long* bmp = bmp_all + (long long)pair * 128;
    const float* pred = (l == 0) ? p13 : (l == 1) ? p26 : p52;

    float loss = 0.f;
    int c = blk * 256 + threadIdx.x;
    if (c < nCells) {
        int p_ = c / 3;
        int a  = c - p_ * 3;
        int h  = p_ / S;
        int w  = p_ - h * S;
        float Sf = (float)S;
        float aw = d_anc[l * 3 + a][0];
        float ah = d_anc[l * 3 + a][1];

        const float* pc = pred + (long long)(b * S * S + p_) * 255 + a * 85;
        float v0 = pc[0], v1 = pc[1], v2 = pc[2], v3 = pc[3], v4 = pc[4];

        float conf = 1.f / (1.f + expf(-v0));
        float px = (1.f / (1.f + expf(-v1)) + (float)w) / Sf;
        float py = (1.f / (1.f + expf(-v2)) + (float)h) / Sf;
        float pw = expf(v3) * aw / Sf;
        float ph = expf(v4) * ah / Sf;

        unsigned long long word = bmp[c >> 6];
        bool obj = (word >> (c & 63)) & 1ULL;

        if (obj) {
            // positive cell: conf + xy + wh + cls losses (ignore irrelevant)
            loss += bce_f(1.f, conf);
            const float* yc = yt + (long long)(b * 3549 + d_n0tab[l]) * 255
                                 + (long long)c * 85;
            float t1 = yc[1], t2 = yc[2], t3 = yc[3], t4 = yc[4];
            float sc = 2.f - t3 * t4;
            float tx = t1 * Sf - (float)w;
            float ty = t2 * Sf - (float)h;
            loss += sc * (bce_f(tx, px) + bce_f(ty, py));
            float twx = logf(t3 / aw * 416.f);
            float twy = logf(t4 / ah * 416.f);
            loss += sc * 0.5f * ((twx - pw) * (twx - pw) + (twy - ph) * (twy - ph));
            for (int k = 0; k < 80; ++k) {
                float t = yc[5 + k];
                float x = 1.f / (1.f + expf(-pc[5 + k]));
                loss += bce_f(t, x);
            }
        } else {
            // negative cell: conf loss gated by IoU-ignore vs gt boxes
            float pxmin = px - pw * 0.5f, pxmax = px + pw * 0.5f;
            float pymin = py - ph * 0.5f, pymax = py + ph * 0.5f;
            float parea = pw * ph;
            float best = -1.f;  // stands in for -inf (all IoUs >= 0)
            for (int i = 0; i < count; ++i) {
                float gx = sb[i * 4 + 0], gy = sb[i * 4 + 1];
                float gw = sb[i * 4 + 2], gh = sb[i * 4 + 3];
                float iw = fminf(pxmax, gx + gw * 0.5f) - fmaxf(pxmin, gx - gw * 0.5f);
                float ih = fminf(pymax, gy + gh * 0.5f) - fmaxf(pymin, gy - gh * 0.5f);
                iw = fmaxf(iw, 0.f);
                ih = fmaxf(ih, 0.f);
                float inter = iw * ih;
                float iou = inter / (parea + gw * gh - inter);
                best = fmaxf(best, iou);
            }
            if (best < 0.5f) loss += bce_f(0.f, conf);
        }
    }

    // block reduction -> atomicAdd per block
    for (int off = 32; off > 0; off >>= 1)
        loss += __shfl_down(loss, off, 64);
    __shared__ float wsum[4];
    if ((threadIdx.x & 63) == 0) wsum[threadIdx.x >> 6] = loss;
    __syncthreads();
    if (threadIdx.x == 0)
        atomicAdd(out + b, wsum[0] + wsum[1] + wsum[2] + wsum[3]);
}

extern "C" void kernel_launch(void* const* d_in, const int* in_sizes, int n_in,
                              void* d_out, int out_size, void* d_ws, size_t ws_size,
                              hipStream_t stream) {
    const float* yt  = (const float*)d_in[0];
    const float* p13 = (const float*)d_in[1];
    const float* p26 = (const float*)d_in[2];
    const float* p52 = (const float*)d_in[3];
    float* out = (float*)d_out;

    // workspace layout: counts[96] | pad to 512 | boxes[96][64][4] f32 | bitmap[96][128] u64
    int* counts = (int*)d_ws;
    float* boxes = (float*)((char*)d_ws + 512);
    unsigned long long* bmp =
        (unsigned long long*)((char*)d_ws + 512 + NPAIR * MAXB * 4 * sizeof(float));

    gather_k<<<NPAIR, 256, 0, stream>>>(yt, boxes, counts, bmp, out);
    loss_k<<<32 * 42, 256, 0, stream>>>(yt, p13, p26, p52, boxes, counts, bmp, out);
}

// Round 2
// 245.187 us; speedup vs baseline: 1.3587x; 1.3587x over previous
//
#include <hip/hip_runtime.h>

#define NPAIR 96
#define MAXB 64
#define CAP 256

__constant__ float c_anc[9][2] = {
    {116.f, 90.f}, {156.f, 198.f}, {373.f, 326.f},
    { 30.f, 61.f}, { 62.f, 45.f}, { 59.f, 119.f},
    { 10.f, 13.f}, { 16.f, 30.f}, { 33.f, 23.f}};

__device__ __forceinline__ float sigm(float x) { return 1.f / (1.f + expf(-x)); }

// bce_logits(t, x) = max(x,0) - x*t + log1p(exp(-|x|)); exp(-|x|) in (0,1] so
// plain logf(1+z) is accurate (no cancellation).
__device__ __forceinline__ float bce_f(float t, float x) {
    return fmaxf(x, 0.f) - x * t + logf(1.f + expf(-fabsf(x)));
}

// block j (0..41 within a batch) -> layer l, chunk blk, grid S, row offset n0
__device__ __forceinline__ void map_block(int j, int& l, int& blk, int& S, int& n0) {
    if (j < 2)       { l = 0; blk = j;      S = 13; n0 = 0;   }
    else if (j < 10) { l = 1; blk = j - 2;  S = 26; n0 = 169; }
    else             { l = 2; blk = j - 10; S = 52; n0 = 845; }
}

// ---------------- scan: obj bitmap only (1344 blocks, 1 cell/thread) --------
__global__ __launch_bounds__(256) void scan_k(
    const float* __restrict__ yt, unsigned long long* __restrict__ bmp_all,
    float* __restrict__ out)
{
    int bid = blockIdx.x;
    int tid = threadIdx.x;
    if (bid == 0 && tid < 32) out[tid] = 0.f;
    int b = bid / 42;
    int j = bid - b * 42;
    int l, blk, S, n0;
    map_block(j, l, blk, S, n0);
    int nCells = S * S * 3;
    int c = blk * 256 + tid;
    const float* ybase = yt + (long long)(b * 3549 + n0) * 255;
    float ov = (c < nCells) ? ybase[(long long)c * 85] : 0.f;
    unsigned long long m = __ballot(ov > 0.5f);
    if ((tid & 63) == 0)
        bmp_all[(long long)(b * 3 + l) * 128 + (c >> 6)] = m;
}

// ---------------- pos: sorted positive list + ordered boxes + positive losses
__global__ __launch_bounds__(256) void pos_k(
    const float* __restrict__ yt,
    const float* __restrict__ p13, const float* __restrict__ p26,
    const float* __restrict__ p52,
    float4* __restrict__ oboxes, int* __restrict__ counts,
    const unsigned long long* __restrict__ bmp_all,
    float* __restrict__ out)
{
    int pair = blockIdx.x;
    int b = pair / 3;
    int l = pair - b * 3;
    int S  = (l == 0) ? 13 : (l == 1) ? 26 : 52;
    int n0 = (l == 0) ? 0  : (l == 1) ? 169 : 845;
    int nwords = (l == 0) ? 8 : (l == 1) ? 32 : 128;
    float Sf = (float)S;
    const float* ybase = yt + (long long)(b * 3549 + n0) * 255;
    const float* pred  = (l == 0) ? p13 : (l == 1) ? p26 : p52;
    const float* pbase = pred + (long long)b * S * S * 255;
    const unsigned long long* bmp = bmp_all + (long long)pair * 128;

    __shared__ int spc[128];
    __shared__ int sidx[CAP];
    __shared__ int stot;

    int tid = threadIdx.x;
    unsigned long long w = 0ULL;
    if (tid < 128) {
        w = (tid < nwords) ? bmp[tid] : 0ULL;
        spc[tid] = __popcll(w);
    }
    __syncthreads();
    if (tid < 128) {
        int base = 0;
        for (int jj = 0; jj < tid; ++jj) base += spc[jj];  // LDS broadcast
        unsigned long long ww = w;
        while (ww) {
            int bit = __ffsll((long long)ww) - 1;
            if (base < CAP) sidx[base] = tid * 64 + bit;
            ++base;
            ww &= ww - 1;
        }
        if (tid == 127) stot = base;  // total positives (untruncated)
    }
    __syncthreads();

    int TC = stot < CAP ? stot : CAP;
    int MB = TC < MAXB ? TC : MAXB;
    if (tid == 0) counts[pair] = MB;
    if (tid < MB) {
        int idx = sidx[tid];
        const float* yc = ybase + (long long)idx * 85;
        oboxes[pair * MAXB + tid] = make_float4(yc[1], yc[2], yc[3], yc[4]);
    }

    // positive losses: one wave per positive (round-robin), 80 cls channels
    // spread over lanes; lane 0 does the 5 box/conf terms.
    int wv = tid >> 6, lane = tid & 63;
    float wsum = 0.f;
    for (int i = wv; i < TC; i += 4) {
        int idx = sidx[i];
        const float* yc = ybase + (long long)idx * 85;
        const float* pc = pbase + (long long)idx * 85;
        float part = bce_f(yc[5 + lane], sigm(pc[5 + lane]));
        if (lane < 16)
            part += bce_f(yc[69 + lane], sigm(pc[69 + lane]));
        if (lane == 0) {
            int p_ = idx / 3, a = idx - p_ * 3;
            int gh = p_ / S, gw = p_ - gh * S;
            float aw = c_anc[l * 3 + a][0], ah = c_anc[l * 3 + a][1];
            float v0 = pc[0], v1 = pc[1], v2 = pc[2], v3 = pc[3], v4 = pc[4];
            float t1 = yc[1], t2 = yc[2], t3 = yc[3], t4 = yc[4];
            part += bce_f(1.f, sigm(v0));
            float sc = 2.f - t3 * t4;
            float px = (sigm(v1) + (float)gw) / Sf;
            float py = (sigm(v2) + (float)gh) / Sf;
            part += sc * (bce_f(t1 * Sf - (float)gw, px) +
                          bce_f(t2 * Sf - (float)gh, py));
            float pw = expf(v3) * aw / Sf, ph = expf(v4) * ah / Sf;
            float twx = logf(t3 / aw * 416.f), twy = logf(t4 / ah * 416.f);
            part += sc * 0.5f * ((twx - pw) * (twx - pw) + (twy - ph) * (twy - ph));
        }
        for (int off = 32; off > 0; off >>= 1)
            part += __shfl_down(part, off, 64);
        if (lane == 0) wsum += part;
    }
    if (lane == 0) atomicAdd(out + b, wsum);
}

// ---------------- neg: conf loss with IoU-ignore (1344 blocks) --------------
__global__ __launch_bounds__(256) void neg_k(
    const float* __restrict__ p13, const float* __restrict__ p26,
    const float* __restrict__ p52,
    const float4* __restrict__ oboxes, const int* __restrict__ counts,
    const unsigned long long* __restrict__ bmp_all,
    float* __restrict__ out)
{
    int bid = blockIdx.x;
    int tid = threadIdx.x;
    int b = bid / 42;
    int j = bid - b * 42;
    int l, blk, S, n0;
    map_block(j, l, blk, S, n0);
    (void)n0;
    int nCells = S * S * 3;
    int pair = b * 3 + l;
    float Sf = (float)S;
    const float* pred  = (l == 0) ? p13 : (l == 1) ? p26 : p52;
    const float* pbase = pred + (long long)b * S * S * 255;

    __shared__ float sxmin[MAXB], sxmax[MAXB], symin[MAXB], symax[MAXB], sba[MAXB];
    int count = counts[pair];
    if (tid < count) {
        float4 g = oboxes[pair * MAXB + tid];
        sxmin[tid] = g.x - g.z * 0.5f;
        sxmax[tid] = g.x + g.z * 0.5f;
        symin[tid] = g.y - g.w * 0.5f;
        symax[tid] = g.y + g.w * 0.5f;
        sba[tid]   = g.z * g.w;
    }
    __syncthreads();

    float loss = 0.f;
    int c = blk * 256 + tid;
    if (c < nCells) {
        unsigned long long word = bmp_all[(long long)pair * 128 + (c >> 6)];
        if (!((word >> (c & 63)) & 1ULL)) {
            const float* pc = pbase + (long long)c * 85;
            float v0 = pc[0];
            if (count == 0) {
                loss = bce_f(0.f, sigm(v0));
            } else {
                float v1 = pc[1], v2 = pc[2], v3 = pc[3], v4 = pc[4];
                int p_ = c / 3, a = c - p_ * 3;
                int gh = p_ / S, gw = p_ - gh * S;
                float aw = c_anc[l * 3 + a][0], ah = c_anc[l * 3 + a][1];
                float px = (sigm(v1) + (float)gw) / Sf;
                float py = (sigm(v2) + (float)gh) / Sf;
                float pw = expf(v3) * aw / Sf, ph = expf(v4) * ah / Sf;
                float pxmin = px - pw * 0.5f, pxmax = px + pw * 0.5f;
                float pymin = py - ph * 0.5f, pymax = py + ph * 0.5f;
                float parea = pw * ph;
                bool hit = false;
                // iou >= 0.5  <=>  2*inter >= union = pa+ba-inter  <=>  3*inter >= pa+ba
#pragma unroll 4
                for (int i = 0; i < count; ++i) {
                    float iw = fminf(pxmax, sxmax[i]) - fmaxf(pxmin, sxmin[i]);
                    float ih = fminf(pymax, symax[i]) - fmaxf(pymin, symin[i]);
                    float inter = fmaxf(iw, 0.f) * fmaxf(ih, 0.f);
                    hit = hit || (3.f * inter >= parea + sba[i]);
                }
                if (!hit) loss = bce_f(0.f, sigm(v0));
            }
        }
    }

    for (int off = 32; off > 0; off >>= 1)
        loss += __shfl_down(loss, off, 64);
    __shared__ float wsum[4];
    if ((tid & 63) == 0) wsum[tid >> 6] = loss;
    __syncthreads();
    if (tid == 0)
        atomicAdd(out + b, wsum[0] + wsum[1] + wsum[2] + wsum[3]);
}

extern "C" void kernel_launch(void* const* d_in, const int* in_sizes, int n_in,
                              void* d_out, int out_size, void* d_ws, size_t ws_size,
                              hipStream_t stream) {
    (void)in_sizes; (void)n_in; (void)out_size; (void)ws_size;
    const float* yt  = (const float*)d_in[0];
    const float* p13 = (const float*)d_in[1];
    const float* p26 = (const float*)d_in[2];
    const float* p52 = (const float*)d_in[3];
    float* out = (float*)d_out;

    // ws layout: bitmap[96][128] u64 | oboxes[96][64] float4 | counts[96] int
    unsigned long long* bmp = (unsigned long long*)d_ws;
    float4* oboxes = (float4*)((char*)d_ws + NPAIR * 128 * 8);
    int* counts    = (int*)((char*)d_ws + NPAIR * 128 * 8 + NPAIR * MAXB * 16);

    scan_k<<<32 * 42, 256, 0, stream>>>(yt, bmp, out);
    pos_k<<<NPAIR, 256, 0, stream>>>(yt, p13, p26, p52, oboxes, counts, bmp, out);
    neg_k<<<32 * 42, 256, 0, stream>>>(p13, p26, p52, oboxes, counts, bmp, out);
}